// Round 1
// baseline (159.350 us; speedup 1.0000x reference)
//
#include <hip/hip_runtime.h>

// out[b,s,f] = in1[b,s,f] * w[f] + in2[b,s,f] * (1 - w[f])
// B=4, S=4096, F=4096  -> 67,108,864 f32 elements, memory-bound.
// float4 vectorization: 16,777,216 float4 elems; weight float4 index = i & 1023.

__global__ __launch_bounds__(256) void merger_kernel(
    const float4* __restrict__ a,
    const float4* __restrict__ b,
    const float4* __restrict__ w,
    float4* __restrict__ out,
    int n4) {
    const int f4mask = 1023;  // (4096/4) - 1
    int idx = blockIdx.x * blockDim.x + threadIdx.x;
    int stride = gridDim.x * blockDim.x;
    for (int i = idx; i < n4; i += stride) {
        float4 av = a[i];
        float4 bv = b[i];
        float4 wv = w[i & f4mask];
        float4 o;
        o.x = av.x * wv.x + bv.x * (1.0f - wv.x);
        o.y = av.y * wv.y + bv.y * (1.0f - wv.y);
        o.z = av.z * wv.z + bv.z * (1.0f - wv.z);
        o.w = av.w * wv.w + bv.w * (1.0f - wv.w);
        out[i] = o;
    }
}

extern "C" void kernel_launch(void* const* d_in, const int* in_sizes, int n_in,
                              void* d_out, int out_size, void* d_ws, size_t ws_size,
                              hipStream_t stream) {
    const float4* a = (const float4*)d_in[0];
    const float4* b = (const float4*)d_in[1];
    const float4* w = (const float4*)d_in[2];
    float4* out = (float4*)d_out;
    int n4 = out_size / 4;  // 16,777,216

    const int block = 256;
    const int grid = 2048;  // 256 CUs x 8 blocks/CU; grid-stride covers the rest
    merger_kernel<<<grid, block, 0, stream>>>(a, b, w, out, n4);
}

// Round 3
// 139.560 us; speedup vs baseline: 1.1418x; 1.1418x over previous
//
#include <hip/hip_runtime.h>

// out[b,s,f] = in1[b,s,f] * w[f] + in2[b,s,f] * (1 - w[f])
// B=4, S=4096, F=4096 -> 67,108,864 f32 = 16,777,216 float4. Memory-bound.
//
// Each block handles one contiguous chunk of 1024 vec4 (= one full 4096-float
// feature row); thread t takes vec4s {t, t+256, t+512, t+768}. All 8 big
// loads (4x a, 4x b) are independent and issued before any use -> deep MLP.
// Weight vec4 index is block-invariant (u*256+t), L1-resident 16 KB.
// Output streamed with nontemporal stores to keep L3 for the inputs.
//
// Uses clang native vector (ext_vector_type) instead of HIP float4 because
// __builtin_nontemporal_store requires a scalar-or-clang-vector pointee.

typedef float fvec4 __attribute__((ext_vector_type(4)));

__global__ __launch_bounds__(256) void merger_kernel(
    const fvec4* __restrict__ a,
    const fvec4* __restrict__ b,
    const fvec4* __restrict__ w,
    fvec4* __restrict__ out) {
    const int t = threadIdx.x;
    const int base = blockIdx.x * 1024 + t;  // max ~16.8M, fits int

    // Weight fragments: block-invariant addresses, L1-hot after first touch.
    const fvec4 wv0 = w[t];
    const fvec4 wv1 = w[t + 256];
    const fvec4 wv2 = w[t + 512];
    const fvec4 wv3 = w[t + 768];

    // 8 independent global loads in flight.
    const fvec4 av0 = a[base];
    const fvec4 av1 = a[base + 256];
    const fvec4 av2 = a[base + 512];
    const fvec4 av3 = a[base + 768];
    const fvec4 bv0 = b[base];
    const fvec4 bv1 = b[base + 256];
    const fvec4 bv2 = b[base + 512];
    const fvec4 bv3 = b[base + 768];

    // a*w + b*(1-w), elementwise on the 4-vectors.
    const fvec4 o0 = av0 * wv0 + bv0 * (1.0f - wv0);
    const fvec4 o1 = av1 * wv1 + bv1 * (1.0f - wv1);
    const fvec4 o2 = av2 * wv2 + bv2 * (1.0f - wv2);
    const fvec4 o3 = av3 * wv3 + bv3 * (1.0f - wv3);

    __builtin_nontemporal_store(o0, &out[base]);
    __builtin_nontemporal_store(o1, &out[base + 256]);
    __builtin_nontemporal_store(o2, &out[base + 512]);
    __builtin_nontemporal_store(o3, &out[base + 768]);
}

extern "C" void kernel_launch(void* const* d_in, const int* in_sizes, int n_in,
                              void* d_out, int out_size, void* d_ws, size_t ws_size,
                              hipStream_t stream) {
    const fvec4* a = (const fvec4*)d_in[0];
    const fvec4* b = (const fvec4*)d_in[1];
    const fvec4* w = (const fvec4*)d_in[2];
    fvec4* out = (fvec4*)d_out;
    // out_size = 67,108,864 floats = 16,777,216 vec4; 1024 vec4 per block.
    const int grid = out_size / (4 * 1024);  // 16384 blocks, exact cover
    merger_kernel<<<grid, 256, 0, stream>>>(a, b, w, out);
}